// Round 12
// baseline (310.177 us; speedup 1.0000x reference)
//
#include <hip/hip_runtime.h>
#include <hip/hip_bf16.h>

#define N_NODES 500000
#define N_ELEM  2000000

#define CSH   10                        // 1024 nodes per bin
#define NPBIN (1 << CSH)                // 1024
#define NBIN  ((N_NODES + NPBIN - 1) >> CSH)   // 489
#define SBLK  256                       // emit blocks (and count partition)

typedef unsigned int u32x4 __attribute__((ext_vector_type(4)));
typedef float f32x2 __attribute__((ext_vector_type(2)));

// ws layout:
//   [0,64)              double accum[8]
//   [1024, +4*(NBIN+1)) int off[NBIN+1]
//   [8192, +4*NBIN)     int cnt[NBIN]
//   [16384, +250368)    u16 hist[NBIN][SBLK]
//   [266752, +250368)   u16 offs[SBLK][NBIN]
//   [524288, +8MB)      uint4 pred16[N_NODES]
//   [8524288, +64MB)    uint4 entries[2*N_ELEM]
#define HIST_OFF 16384ull
#define OFFS_OFF 266752ull
#define P16_OFF  524288ull
#define ENT_OFF  (P16_OFF + 16ull * N_NODES)
#define WS_NEED  (ENT_OFF + 16ull * 2 * N_ELEM)

__device__ __forceinline__ float wave_reduce(float v) {
    #pragma unroll
    for (int o = 32; o > 0; o >>= 1) v += __shfl_down(v, o, 64);
    return v;
}

template<int NW>
__device__ __forceinline__ void block_reduce_add(float v, double* dst, float* sm) {
    int lane = threadIdx.x & 63;
    int wave = threadIdx.x >> 6;
    v = wave_reduce(v);
    if (lane == 0) sm[wave] = v;
    __syncthreads();
    if (threadIdx.x == 0) {
        float s = 0.f;
        #pragma unroll
        for (int w = 0; w < NW; ++w) s += sm[w];
        atomicAdd(dst, (double)s);
    }
    __syncthreads();
}

__device__ __forceinline__ unsigned int pack2(float a, float b) {
    unsigned int ua = (__float_as_uint(a) + 0x8000u) >> 16;
    unsigned int ub = (__float_as_uint(b) + 0x8000u) & 0xFFFF0000u;
    return ua | ub;
}
__device__ __forceinline__ float unlo(unsigned int u) {
    return __uint_as_float(u << 16);
}
__device__ __forceinline__ float unhi(unsigned int u) {
    return __uint_as_float(u & 0xFFFF0000u);
}

// ---------------- beam math ----------------
__device__ __forceinline__ void beam_core(
    float x0, float x1, float x2,
    float u0i, float u1i, float u2i, float t0i, float t1i, float t2i,
    float u0j, float u1j, float u2j, float t0j, float t1j, float t2j,
    float L, float E, float A, float I,
    float& F0, float& F1, float& F2,
    float& Mi0, float& Mi1, float& Mi2,
    float& Mj0, float& Mj1, float& Mj2)
{
    bool par = fabsf(x1) > 0.99f;
    float r1 = par ? 0.f : 1.f;
    float r2 = par ? 1.f : 0.f;
    float z0 = x1 * r2 - x2 * r1;
    float z1 = -x0 * r2;
    float z2 = x0 * r1;
    float zn = fmaxf(sqrtf(z0 * z0 + z1 * z1 + z2 * z2), 1e-8f);
    float izn = 1.f / zn;
    z0 *= izn; z1 *= izn; z2 *= izn;
    float y0 = z1 * x2 - z2 * x1;
    float y1 = z2 * x0 - z0 * x2;
    float y2 = z0 * x1 - z1 * x0;
    float yn = fmaxf(sqrtf(y0 * y0 + y1 * y1 + y2 * y2), 1e-8f);
    float iyn = 1.f / yn;
    y0 *= iyn; y1 *= iyn; y2 *= iyn;

    float du0 = u0j - u0i;
    float du1 = u1j - u1i;
    float du2 = u2j - u2i;

    float EA = E * A;
    float EI = E * I;
    float invL = 1.f / L;
    float invL2 = invL * invL;
    float invL3 = invL2 * invL;

    float axial = du0 * x0 + du1 * x1 + du2 * x2;
    float Naxial = EA * invL * axial;

    float k12 = 12.f * EI * invL3;
    float k6  = 6.f * EI * invL2;
    float kL  = EI * invL;

    float dwz = du0 * z0 + du1 * z1 + du2 * z2;
    float tyi = t0i * y0 + t1i * y1 + t2i * y2;
    float tyj = t0j * y0 + t1j * y1 + t2j * y2;
    float Vz  = k12 * dwz + k6 * (tyi + tyj);
    float Myi = k6 * dwz + kL * (2.f * tyi + tyj);
    float Myj = k6 * dwz + kL * (tyi + 2.f * tyj);

    float dwy = du0 * y0 + du1 * y1 + du2 * y2;
    float tzi = t0i * z0 + t1i * z1 + t2i * z2;
    float tzj = t0j * z0 + t1j * z1 + t2j * z2;
    float Vy  = k12 * dwy + k6 * (tzi + tzj);
    float Mzi = k6 * dwy + kL * (2.f * tzi + tzj);
    float Mzj = k6 * dwy + kL * (tzi + 2.f * tzj);

    F0 = Naxial * x0 + Vz * z0 + Vy * y0;
    F1 = Naxial * x1 + Vz * z1 + Vy * y1;
    F2 = Naxial * x2 + Vz * z2 + Vy * y2;

    Mi0 = Myi * y0 + Mzi * z0;
    Mi1 = Myi * y1 + Mzi * z1;
    Mi2 = Myi * y2 + Mzi * z2;
    Mj0 = Myj * y0 + Mzj * z0;
    Mj1 = Myj * y1 + Mzj * z1;
    Mj2 = Myj * y2 + Mzj * z2;
}

__device__ __forceinline__ void beam_full(
    float x0, float x1, float x2,
    const float* __restrict__ pi, const float* __restrict__ pj,
    float L, float E, float A, float I,
    float& F0, float& F1, float& F2,
    float& Mi0, float& Mi1, float& Mi2,
    float& Mj0, float& Mj1, float& Mj2)
{
    float2 a0 = *(const float2*)(pi + 0);
    float2 a1 = *(const float2*)(pi + 2);
    float2 a2 = *(const float2*)(pi + 4);
    float2 b0 = *(const float2*)(pj + 0);
    float2 b1 = *(const float2*)(pj + 2);
    float2 b2 = *(const float2*)(pj + 4);
    beam_core(x0, x1, x2,
              a0.x, a0.y, a1.x, a1.y, a2.x, a2.y,
              b0.x, b0.y, b1.x, b1.y, b2.x, b2.y,
              L, E, A, I,
              F0, F1, F2, Mi0, Mi1, Mi2, Mj0, Mj1, Mj2);
}

// ---------------- prep: pack pred into 16B bf16 rows (NT reads) ----------------

__global__ __launch_bounds__(256) void prep_kernel(
    const float* __restrict__ pred, uint4* __restrict__ pred16)
{
    int n = blockIdx.x * 256 + threadIdx.x;
    if (n >= N_NODES) return;
    const f32x2* p2 = (const f32x2*)(pred + 6l * n);
    f32x2 a0 = __builtin_nontemporal_load(p2 + 0);
    f32x2 a1 = __builtin_nontemporal_load(p2 + 1);
    f32x2 a2 = __builtin_nontemporal_load(p2 + 2);
    uint4 r;
    r.x = pack2(a0.x, a0.y);
    r.y = pack2(a1.x, a1.y);
    r.z = pack2(a2.x, a2.y);
    r.w = 0u;
    pred16[n] = r;   // regular store: reused by emit gathers
}

// ---------------- count: per-emit-block histogram (NT conn reads) ----------------

__global__ __launch_bounds__(256) void count_kernel(
    const int* __restrict__ conn, unsigned short* __restrict__ hist)
{
    __shared__ int bins[NBIN];
    for (int i = threadIdx.x; i < NBIN; i += 256) bins[i] = 0;
    __syncthreads();

    int b = blockIdx.x;
    int per = (N_ELEM + SBLK - 1) / SBLK;
    int e0 = b * per;
    int e1 = min(e0 + per, N_ELEM);

    for (int e = e0 + threadIdx.x; e < e1; e += 256) {
        long long cc = __builtin_nontemporal_load((const long long*)(conn + 2l * e));
        int cx = (int)(cc & 0xffffffffll);
        int cy = (int)(cc >> 32);
        atomicAdd(&bins[cx >> CSH], 1);
        atomicAdd(&bins[cy >> CSH], 1);
    }
    __syncthreads();
    for (int k = threadIdx.x; k < NBIN; k += 256)
        hist[(size_t)k * SBLK + b] = (unsigned short)bins[k];
}

// per-bin scan across the 256 emit blocks
__global__ __launch_bounds__(256) void scan2_kernel(
    const unsigned short* __restrict__ hist,
    unsigned short* __restrict__ offs, int* __restrict__ cnt)
{
    __shared__ int s[256];
    int k = blockIdx.x, t = threadIdx.x;
    int v = hist[(size_t)k * SBLK + t];
    s[t] = v;
    __syncthreads();
    for (int o = 1; o < 256; o <<= 1) {
        int tv = (t >= o) ? s[t - o] : 0;
        __syncthreads();
        s[t] += tv;
        __syncthreads();
    }
    offs[(size_t)t * NBIN + k] = (unsigned short)(s[t] - v);
    if (t == 255) cnt[k] = s[t];
}

__global__ __launch_bounds__(512) void scan_kernel(
    const int* __restrict__ cnt, int* __restrict__ off)
{
    __shared__ int s[512];
    int tid = threadIdx.x;
    int v = (tid < NBIN) ? cnt[tid] : 0;
    s[tid] = v;
    __syncthreads();
    for (int o = 1; o < 512; o <<= 1) {
        int t = (tid >= o) ? s[tid - o] : 0;
        __syncthreads();
        s[tid] += t;
        __syncthreads();
    }
    if (tid < NBIN) off[tid] = s[tid] - v;
    if (tid == 511) off[NBIN] = s[511];
}

// ---------------- emit: NT streams in, NT payload out ----------------

__global__ __launch_bounds__(1024) void emit_kernel(
    const uint4* __restrict__ pred16,
    const int* __restrict__ conn,
    const float* __restrict__ dirs,
    const float* __restrict__ L_, const float* __restrict__ E_,
    const float* __restrict__ A_, const float* __restrict__ I_,
    const int* __restrict__ off, const unsigned short* __restrict__ offs,
    uint4* __restrict__ ents, double* __restrict__ accum)
{
    __shared__ int bins[NBIN];
    __shared__ float sm[16];
    int b = blockIdx.x;
    for (int i = threadIdx.x; i < NBIN; i += 1024)
        bins[i] = off[i] + (int)offs[(size_t)b * NBIN + i];
    __syncthreads();

    int per = (N_ELEM + SBLK - 1) / SBLK;
    int e0 = b * per;
    int e1 = min(e0 + per, N_ELEM);

    float ea = 0.f, eil = 0.f;
    for (int e = e0 + threadIdx.x; e < e1; e += 1024) {
        long long cc = __builtin_nontemporal_load((const long long*)(conn + 2l * e));
        int cx = (int)(cc & 0xffffffffll);
        int cy = (int)(cc >> 32);
        uint4 pi = pred16[cx];            // regular load: pred16 is reused, keep in L2
        uint4 pj = pred16[cy];
        float x0 = __builtin_nontemporal_load(dirs + 3l * e + 0);
        float x1 = __builtin_nontemporal_load(dirs + 3l * e + 1);
        float x2 = __builtin_nontemporal_load(dirs + 3l * e + 2);
        float L = __builtin_nontemporal_load(L_ + e);
        float E = __builtin_nontemporal_load(E_ + e);
        float A = __builtin_nontemporal_load(A_ + e);
        float I = __builtin_nontemporal_load(I_ + e);
        ea  += E * A;
        eil += E * I / L;
        float F0, F1, F2, Mi0, Mi1, Mi2, Mj0, Mj1, Mj2;
        beam_core(x0, x1, x2,
                  unlo(pi.x), unhi(pi.x), unlo(pi.y), unhi(pi.y), unlo(pi.z), unhi(pi.z),
                  unlo(pj.x), unhi(pj.x), unlo(pj.y), unhi(pj.y), unlo(pj.z), unhi(pj.z),
                  L, E, A, I,
                  F0, F1, F2, Mi0, Mi1, Mi2, Mj0, Mj1, Mj2);

        int pi_ = atomicAdd(&bins[cx >> CSH], 1);
        u32x4 ei = {pack2(F0, F1), pack2(F2, Mi0), pack2(Mi1, Mi2),
                    (unsigned int)(cx & (NPBIN - 1))};
        __builtin_nontemporal_store(ei, (u32x4*)(ents + pi_));

        int pj_ = atomicAdd(&bins[cy >> CSH], 1);
        u32x4 ej = {pack2(-F0, -F1), pack2(-F2, Mj0), pack2(Mj1, Mj2),
                    (unsigned int)(cy & (NPBIN - 1))};
        __builtin_nontemporal_store(ej, (u32x4*)(ents + pj_));
    }
    block_reduce_add<16>(ea,  &accum[0], sm);
    block_reduce_add<16>(eil, &accum[1], sm);
}

// ---------------- bin accumulate via ds_pk_add_bf16 + fused node loss ----------------

__global__ __launch_bounds__(1024) void binacc_kernel(
    const uint4* __restrict__ ents,
    const int* __restrict__ off,
    const float* __restrict__ line_load,
    const float* __restrict__ bc_disp,
    const float* __restrict__ bc_rot,
    double* __restrict__ accum)
{
    __shared__ unsigned int acc3[NPBIN * 3];   // 12 KB, each word = 2 x bf16
    __shared__ float sm[16];
    int b = blockIdx.x;
    for (int i = threadIdx.x; i < NPBIN * 3; i += 1024) acc3[i] = 0u;
    __syncthreads();

    int s0 = off[b], s1 = off[b + 1];
    int nbase = b << CSH;
    unsigned int lds_base = (unsigned int)(unsigned long long)(&acc3[0]);

    int k = s0 + threadIdx.x;
    for (; k + 1024 < s1; k += 2048) {
        u32x4 ea_ = __builtin_nontemporal_load((const u32x4*)(ents + k));
        u32x4 eb_ = __builtin_nontemporal_load((const u32x4*)(ents + k + 1024));
        unsigned int aa = lds_base + ea_.w * 12u;
        unsigned int ab = lds_base + eb_.w * 12u;
        asm volatile(
            "ds_pk_add_bf16 %0, %2\n\t"
            "ds_pk_add_bf16 %0, %3 offset:4\n\t"
            "ds_pk_add_bf16 %0, %4 offset:8\n\t"
            "ds_pk_add_bf16 %1, %5\n\t"
            "ds_pk_add_bf16 %1, %6 offset:4\n\t"
            "ds_pk_add_bf16 %1, %7 offset:8"
            :: "v"(aa), "v"(ab),
               "v"(ea_.x), "v"(ea_.y), "v"(ea_.z),
               "v"(eb_.x), "v"(eb_.y), "v"(eb_.z)
            : "memory");
    }
    if (k < s1) {
        u32x4 e = __builtin_nontemporal_load((const u32x4*)(ents + k));
        unsigned int a = lds_base + e.w * 12u;
        asm volatile(
            "ds_pk_add_bf16 %0, %1\n\t"
            "ds_pk_add_bf16 %0, %2 offset:4\n\t"
            "ds_pk_add_bf16 %0, %3 offset:8"
            :: "v"(a), "v"(e.x), "v"(e.y), "v"(e.z)
            : "memory");
    }
    asm volatile("s_waitcnt lgkmcnt(0)" ::: "memory");
    __syncthreads();

    float sqF = 0.f, sqM = 0.f, fd = 0.f, fr = 0.f;
    for (int nl = threadIdx.x; nl < NPBIN; nl += 1024) {
        int n = nbase + nl;
        if (n < N_NODES) {
            float bd = __builtin_nontemporal_load(bc_disp + n);
            float br = __builtin_nontemporal_load(bc_rot + n);
            float fdv = (bd < 0.5f) ? 1.f : 0.f;
            float frv = (br < 0.5f) ? 1.f : 0.f;
            float l0 = __builtin_nontemporal_load(line_load + 3l * n + 0);
            float l1 = __builtin_nontemporal_load(line_load + 3l * n + 1);
            float l2 = __builtin_nontemporal_load(line_load + 3l * n + 2);
            unsigned int w0 = acc3[nl * 3 + 0];
            unsigned int w1 = acc3[nl * 3 + 1];
            unsigned int w2 = acc3[nl * 3 + 2];
            float Fr0 = unlo(w0) + l0;
            float Fr1 = unhi(w0) + l1;
            float Fr2 = unlo(w1) + l2;
            float M0 = unhi(w1);
            float M1 = unlo(w2);
            float M2 = unhi(w2);
            sqF += fdv * (Fr0 * Fr0 + Fr1 * Fr1 + Fr2 * Fr2);
            sqM += frv * (M0 * M0 + M1 * M1 + M2 * M2);
            fd += fdv;
            fr += frv;
        }
    }
    block_reduce_add<16>(sqF, &accum[2], sm);
    block_reduce_add<16>(sqM, &accum[3], sm);
    block_reduce_add<16>(fd,  &accum[4], sm);
    block_reduce_add<16>(fr,  &accum[5], sm);
}

__global__ void final_kernel(const double* __restrict__ accum,
                             float* __restrict__ out)
{
    double F_char = fmax(accum[0] / (double)N_ELEM, 1.0);
    double M_char = fmax(accum[1] / (double)N_ELEM, 1.0);
    double lf = accum[2] / (F_char * F_char) / fmax(accum[4] * 3.0, 1.0);
    double lm = accum[3] / (M_char * M_char) / fmax(accum[5] * 3.0, 1.0);
    out[0] = (float)(lf + lm);
}

// ---------------- fallback: round-1 direct-atomic path ----------------

__global__ __launch_bounds__(256) void elem_kernel_fb(
    const float* __restrict__ pred,
    const int*   __restrict__ conn,
    const float* __restrict__ dirs,
    const float* __restrict__ L_, const float* __restrict__ E_,
    const float* __restrict__ A_, const float* __restrict__ I_,
    float* __restrict__ F_total, float* __restrict__ M_total,
    double* __restrict__ accum)
{
    __shared__ float sm[4];
    int e = blockIdx.x * blockDim.x + threadIdx.x;
    float ea = 0.f, eil = 0.f;
    if (e < N_ELEM) {
        int ni = conn[2 * e], nj = conn[2 * e + 1];
        float x0 = dirs[3 * e + 0], x1 = dirs[3 * e + 1], x2 = dirs[3 * e + 2];
        float L = L_[e], E = E_[e], A = A_[e], I = I_[e];
        float F0, F1, F2, Mi0, Mi1, Mi2, Mj0, Mj1, Mj2;
        beam_full(x0, x1, x2, pred + 6l * ni, pred + 6l * nj, L, E, A, I,
                  F0, F1, F2, Mi0, Mi1, Mi2, Mj0, Mj1, Mj2);
        atomicAdd(&F_total[3l * ni + 0],  F0);
        atomicAdd(&F_total[3l * ni + 1],  F1);
        atomicAdd(&F_total[3l * ni + 2],  F2);
        atomicAdd(&F_total[3l * nj + 0], -F0);
        atomicAdd(&F_total[3l * nj + 1], -F1);
        atomicAdd(&F_total[3l * nj + 2], -F2);
        atomicAdd(&M_total[3l * ni + 0], Mi0);
        atomicAdd(&M_total[3l * ni + 1], Mi1);
        atomicAdd(&M_total[3l * ni + 2], Mi2);
        atomicAdd(&M_total[3l * nj + 0], Mj0);
        atomicAdd(&M_total[3l * nj + 1], Mj1);
        atomicAdd(&M_total[3l * nj + 2], Mj2);
        ea  = E * A;
        eil = E * I / L;
    }
    block_reduce_add<4>(ea,  &accum[0], sm);
    block_reduce_add<4>(eil, &accum[1], sm);
}

__global__ __launch_bounds__(256) void node_kernel_fb(
    const float* __restrict__ F_total, const float* __restrict__ M_total,
    const float* __restrict__ line_load,
    const float* __restrict__ bc_disp, const float* __restrict__ bc_rot,
    double* __restrict__ accum)
{
    __shared__ float sm[4];
    int n = blockIdx.x * blockDim.x + threadIdx.x;
    float sqF = 0.f, sqM = 0.f, fd = 0.f, fr = 0.f;
    if (n < N_NODES) {
        fd = (bc_disp[n] < 0.5f) ? 1.f : 0.f;
        fr = (bc_rot[n]  < 0.5f) ? 1.f : 0.f;
        float Fr0 = F_total[3l * n + 0] + line_load[3l * n + 0];
        float Fr1 = F_total[3l * n + 1] + line_load[3l * n + 1];
        float Fr2 = F_total[3l * n + 2] + line_load[3l * n + 2];
        float M0 = M_total[3l * n + 0];
        float M1 = M_total[3l * n + 1];
        float M2 = M_total[3l * n + 2];
        sqF = fd * (Fr0 * Fr0 + Fr1 * Fr1 + Fr2 * Fr2);
        sqM = fr * (M0 * M0 + M1 * M1 + M2 * M2);
    }
    block_reduce_add<4>(sqF, &accum[2], sm);
    block_reduce_add<4>(sqM, &accum[3], sm);
    block_reduce_add<4>(fd,  &accum[4], sm);
    block_reduce_add<4>(fr,  &accum[5], sm);
}

extern "C" void kernel_launch(void* const* d_in, const int* in_sizes, int n_in,
                              void* d_out, int out_size, void* d_ws, size_t ws_size,
                              hipStream_t stream) {
    const float* pred      = (const float*)d_in[0];
    const int*   conn      = (const int*)  d_in[1];
    const float* dirs      = (const float*)d_in[2];
    const float* lens      = (const float*)d_in[3];
    const float* prop_E    = (const float*)d_in[4];
    const float* prop_A    = (const float*)d_in[5];
    const float* prop_I    = (const float*)d_in[6];
    const float* line_load = (const float*)d_in[7];
    const float* bc_disp   = (const float*)d_in[8];
    const float* bc_rot    = (const float*)d_in[9];

    double* accum = (double*)d_ws;

    if (ws_size >= WS_NEED) {
        int* off = (int*)((char*)d_ws + 1024);
        int* cnt = (int*)((char*)d_ws + 8192);
        unsigned short* hist = (unsigned short*)((char*)d_ws + HIST_OFF);
        unsigned short* offs = (unsigned short*)((char*)d_ws + OFFS_OFF);
        uint4* pred16 = (uint4*)((char*)d_ws + P16_OFF);
        uint4* ents = (uint4*)((char*)d_ws + ENT_OFF);

        hipMemsetAsync(d_ws, 0, 16384, stream);  // accum + off + cnt

        prep_kernel<<<(N_NODES + 255) / 256, 256, 0, stream>>>(pred, pred16);
        count_kernel<<<SBLK, 256, 0, stream>>>(conn, hist);
        scan2_kernel<<<NBIN, 256, 0, stream>>>(hist, offs, cnt);
        scan_kernel<<<1, 512, 0, stream>>>(cnt, off);
        emit_kernel<<<SBLK, 1024, 0, stream>>>(pred16, conn, dirs, lens,
                                               prop_E, prop_A, prop_I,
                                               off, offs, ents, accum);
        binacc_kernel<<<NBIN, 1024, 0, stream>>>(ents, off, line_load, bc_disp,
                                                 bc_rot, accum);
    } else {
        float* F_total = (float*)((char*)d_ws + 64);
        float* M_total = F_total + (size_t)N_NODES * 3;
        hipMemsetAsync(d_ws, 0, 64 + 2ull * N_NODES * 3 * sizeof(float), stream);
        int be = (N_ELEM + 255) / 256;
        elem_kernel_fb<<<be, 256, 0, stream>>>(pred, conn, dirs, lens, prop_E,
                                               prop_A, prop_I, F_total, M_total, accum);
        int bn = (N_NODES + 255) / 256;
        node_kernel_fb<<<bn, 256, 0, stream>>>(F_total, M_total, line_load,
                                               bc_disp, bc_rot, accum);
    }
    final_kernel<<<1, 1, 0, stream>>>(accum, (float*)d_out);
}

// Round 13
// 264.370 us; speedup vs baseline: 1.1733x; 1.1733x over previous
//
#include <hip/hip_runtime.h>
#include <hip/hip_bf16.h>

#define N_NODES 500000
#define N_ELEM  2000000

#define CSH   10                        // 1024 nodes per bin
#define NPBIN (1 << CSH)                // 1024
#define NBIN  ((N_NODES + NPBIN - 1) >> CSH)   // 489
#define SBLK  256                       // emit blocks (and count partition)

typedef unsigned int u32x4 __attribute__((ext_vector_type(4)));

// ws layout:
//   [0,64)              double accum[8]
//   [1024, +4*(NBIN+1)) int off[NBIN+1]
//   [8192, +4*NBIN)     int cnt[NBIN]
//   [16384, +250368)    u16 hist[NBIN][SBLK]
//   [266752, +250368)   u16 offs[SBLK][NBIN]
//   [524288, +8MB)      uint4 pred16[N_NODES]
//   [8524288, +64MB)    uint4 entries[2*N_ELEM]
#define HIST_OFF 16384ull
#define OFFS_OFF 266752ull
#define P16_OFF  524288ull
#define ENT_OFF  (P16_OFF + 16ull * N_NODES)
#define WS_NEED  (ENT_OFF + 16ull * 2 * N_ELEM)

__device__ __forceinline__ float wave_reduce(float v) {
    #pragma unroll
    for (int o = 32; o > 0; o >>= 1) v += __shfl_down(v, o, 64);
    return v;
}

template<int NW>
__device__ __forceinline__ void block_reduce_add(float v, double* dst, float* sm) {
    int lane = threadIdx.x & 63;
    int wave = threadIdx.x >> 6;
    v = wave_reduce(v);
    if (lane == 0) sm[wave] = v;
    __syncthreads();
    if (threadIdx.x == 0) {
        float s = 0.f;
        #pragma unroll
        for (int w = 0; w < NW; ++w) s += sm[w];
        atomicAdd(dst, (double)s);
    }
    __syncthreads();
}

__device__ __forceinline__ unsigned int pack2(float a, float b) {
    unsigned int ua = (__float_as_uint(a) + 0x8000u) >> 16;
    unsigned int ub = (__float_as_uint(b) + 0x8000u) & 0xFFFF0000u;
    return ua | ub;
}
__device__ __forceinline__ float unlo(unsigned int u) {
    return __uint_as_float(u << 16);
}
__device__ __forceinline__ float unhi(unsigned int u) {
    return __uint_as_float(u & 0xFFFF0000u);
}

// ---------------- beam math ----------------
__device__ __forceinline__ void beam_core(
    float x0, float x1, float x2,
    float u0i, float u1i, float u2i, float t0i, float t1i, float t2i,
    float u0j, float u1j, float u2j, float t0j, float t1j, float t2j,
    float L, float E, float A, float I,
    float& F0, float& F1, float& F2,
    float& Mi0, float& Mi1, float& Mi2,
    float& Mj0, float& Mj1, float& Mj2)
{
    bool par = fabsf(x1) > 0.99f;
    float r1 = par ? 0.f : 1.f;
    float r2 = par ? 1.f : 0.f;
    float z0 = x1 * r2 - x2 * r1;
    float z1 = -x0 * r2;
    float z2 = x0 * r1;
    float zn = fmaxf(sqrtf(z0 * z0 + z1 * z1 + z2 * z2), 1e-8f);
    float izn = 1.f / zn;
    z0 *= izn; z1 *= izn; z2 *= izn;
    float y0 = z1 * x2 - z2 * x1;
    float y1 = z2 * x0 - z0 * x2;
    float y2 = z0 * x1 - z1 * x0;
    float yn = fmaxf(sqrtf(y0 * y0 + y1 * y1 + y2 * y2), 1e-8f);
    float iyn = 1.f / yn;
    y0 *= iyn; y1 *= iyn; y2 *= iyn;

    float du0 = u0j - u0i;
    float du1 = u1j - u1i;
    float du2 = u2j - u2i;

    float EA = E * A;
    float EI = E * I;
    float invL = 1.f / L;
    float invL2 = invL * invL;
    float invL3 = invL2 * invL;

    float axial = du0 * x0 + du1 * x1 + du2 * x2;
    float Naxial = EA * invL * axial;

    float k12 = 12.f * EI * invL3;
    float k6  = 6.f * EI * invL2;
    float kL  = EI * invL;

    float dwz = du0 * z0 + du1 * z1 + du2 * z2;
    float tyi = t0i * y0 + t1i * y1 + t2i * y2;
    float tyj = t0j * y0 + t1j * y1 + t2j * y2;
    float Vz  = k12 * dwz + k6 * (tyi + tyj);
    float Myi = k6 * dwz + kL * (2.f * tyi + tyj);
    float Myj = k6 * dwz + kL * (tyi + 2.f * tyj);

    float dwy = du0 * y0 + du1 * y1 + du2 * y2;
    float tzi = t0i * z0 + t1i * z1 + t2i * z2;
    float tzj = t0j * z0 + t1j * z1 + t2j * z2;
    float Vy  = k12 * dwy + k6 * (tzi + tzj);
    float Mzi = k6 * dwy + kL * (2.f * tzi + tzj);
    float Mzj = k6 * dwy + kL * (tzi + 2.f * tzj);

    F0 = Naxial * x0 + Vz * z0 + Vy * y0;
    F1 = Naxial * x1 + Vz * z1 + Vy * y1;
    F2 = Naxial * x2 + Vz * z2 + Vy * y2;

    Mi0 = Myi * y0 + Mzi * z0;
    Mi1 = Myi * y1 + Mzi * z1;
    Mi2 = Myi * y2 + Mzi * z2;
    Mj0 = Myj * y0 + Mzj * z0;
    Mj1 = Myj * y1 + Mzj * z1;
    Mj2 = Myj * y2 + Mzj * z2;
}

__device__ __forceinline__ void beam_full(
    float x0, float x1, float x2,
    const float* __restrict__ pi, const float* __restrict__ pj,
    float L, float E, float A, float I,
    float& F0, float& F1, float& F2,
    float& Mi0, float& Mi1, float& Mi2,
    float& Mj0, float& Mj1, float& Mj2)
{
    float2 a0 = *(const float2*)(pi + 0);
    float2 a1 = *(const float2*)(pi + 2);
    float2 a2 = *(const float2*)(pi + 4);
    float2 b0 = *(const float2*)(pj + 0);
    float2 b1 = *(const float2*)(pj + 2);
    float2 b2 = *(const float2*)(pj + 4);
    beam_core(x0, x1, x2,
              a0.x, a0.y, a1.x, a1.y, a2.x, a2.y,
              b0.x, b0.y, b1.x, b1.y, b2.x, b2.y,
              L, E, A, I,
              F0, F1, F2, Mi0, Mi1, Mi2, Mj0, Mj1, Mj2);
}

// ---------------- prep: pack pred into 16B bf16 rows ----------------

__global__ __launch_bounds__(256) void prep_kernel(
    const float* __restrict__ pred, uint4* __restrict__ pred16)
{
    int n = blockIdx.x * 256 + threadIdx.x;
    if (n >= N_NODES) return;
    const float2* p2 = (const float2*)(pred + 6l * n);
    float2 a0 = p2[0], a1 = p2[1], a2 = p2[2];
    uint4 r;
    r.x = pack2(a0.x, a0.y);
    r.y = pack2(a1.x, a1.y);
    r.z = pack2(a2.x, a2.y);
    r.w = 0u;
    pred16[n] = r;
}

// ---------------- count: per-emit-block histogram ----------------

__global__ __launch_bounds__(256) void count_kernel(
    const int* __restrict__ conn, unsigned short* __restrict__ hist)
{
    __shared__ int bins[NBIN];
    for (int i = threadIdx.x; i < NBIN; i += 256) bins[i] = 0;
    __syncthreads();

    int b = blockIdx.x;
    int per = (N_ELEM + SBLK - 1) / SBLK;
    int e0 = b * per;
    int e1 = min(e0 + per, N_ELEM);
    const int2* c2 = (const int2*)conn;

    for (int e = e0 + threadIdx.x; e < e1; e += 256) {
        int2 c = c2[e];
        atomicAdd(&bins[c.x >> CSH], 1);
        atomicAdd(&bins[c.y >> CSH], 1);
    }
    __syncthreads();
    for (int k = threadIdx.x; k < NBIN; k += 256)
        hist[(size_t)k * SBLK + b] = (unsigned short)bins[k];
}

// per-bin scan across the 256 emit blocks
__global__ __launch_bounds__(256) void scan2_kernel(
    const unsigned short* __restrict__ hist,
    unsigned short* __restrict__ offs, int* __restrict__ cnt)
{
    __shared__ int s[256];
    int k = blockIdx.x, t = threadIdx.x;
    int v = hist[(size_t)k * SBLK + t];
    s[t] = v;
    __syncthreads();
    for (int o = 1; o < 256; o <<= 1) {
        int tv = (t >= o) ? s[t - o] : 0;
        __syncthreads();
        s[t] += tv;
        __syncthreads();
    }
    offs[(size_t)t * NBIN + k] = (unsigned short)(s[t] - v);
    if (t == 255) cnt[k] = s[t];
}

__global__ __launch_bounds__(512) void scan_kernel(
    const int* __restrict__ cnt, int* __restrict__ off)
{
    __shared__ int s[512];
    int tid = threadIdx.x;
    int v = (tid < NBIN) ? cnt[tid] : 0;
    s[tid] = v;
    __syncthreads();
    for (int o = 1; o < 512; o <<= 1) {
        int t = (tid >= o) ? s[tid - o] : 0;
        __syncthreads();
        s[tid] += t;
        __syncthreads();
    }
    if (tid < NBIN) off[tid] = s[tid] - v;
    if (tid == 511) off[NBIN] = s[511];
}

// ---------------- emit: regular loads, NT payload store ----------------

__global__ __launch_bounds__(1024) void emit_kernel(
    const uint4* __restrict__ pred16,
    const int* __restrict__ conn,
    const float* __restrict__ dirs,
    const float* __restrict__ L_, const float* __restrict__ E_,
    const float* __restrict__ A_, const float* __restrict__ I_,
    const int* __restrict__ off, const unsigned short* __restrict__ offs,
    uint4* __restrict__ ents, double* __restrict__ accum)
{
    __shared__ int bins[NBIN];
    __shared__ float sm[16];
    int b = blockIdx.x;
    for (int i = threadIdx.x; i < NBIN; i += 1024)
        bins[i] = off[i] + (int)offs[(size_t)b * NBIN + i];
    __syncthreads();

    int per = (N_ELEM + SBLK - 1) / SBLK;
    int e0 = b * per;
    int e1 = min(e0 + per, N_ELEM);
    const int2* c2 = (const int2*)conn;

    float ea = 0.f, eil = 0.f;
    for (int e = e0 + threadIdx.x; e < e1; e += 1024) {
        int2 c = c2[e];
        uint4 pi = pred16[c.x];
        uint4 pj = pred16[c.y];
        float x0 = dirs[3 * e + 0], x1 = dirs[3 * e + 1], x2 = dirs[3 * e + 2];
        float L = L_[e], E = E_[e], A = A_[e], I = I_[e];
        ea  += E * A;
        eil += E * I / L;
        float F0, F1, F2, Mi0, Mi1, Mi2, Mj0, Mj1, Mj2;
        beam_core(x0, x1, x2,
                  unlo(pi.x), unhi(pi.x), unlo(pi.y), unhi(pi.y), unlo(pi.z), unhi(pi.z),
                  unlo(pj.x), unhi(pj.x), unlo(pj.y), unhi(pj.y), unlo(pj.z), unhi(pj.z),
                  L, E, A, I,
                  F0, F1, F2, Mi0, Mi1, Mi2, Mj0, Mj1, Mj2);

        int pi_ = atomicAdd(&bins[c.x >> CSH], 1);
        u32x4 ei = {pack2(F0, F1), pack2(F2, Mi0), pack2(Mi1, Mi2),
                    (unsigned int)(c.x & (NPBIN - 1))};
        __builtin_nontemporal_store(ei, (u32x4*)(ents + pi_));

        int pj_ = atomicAdd(&bins[c.y >> CSH], 1);
        u32x4 ej = {pack2(-F0, -F1), pack2(-F2, Mj0), pack2(Mj1, Mj2),
                    (unsigned int)(c.y & (NPBIN - 1))};
        __builtin_nontemporal_store(ej, (u32x4*)(ents + pj_));
    }
    block_reduce_add<16>(ea,  &accum[0], sm);
    block_reduce_add<16>(eil, &accum[1], sm);
}

// ---------------- bin accumulate via ds_pk_add_bf16 + fused node loss ----------------

__global__ __launch_bounds__(1024) void binacc_kernel(
    const uint4* __restrict__ ents,
    const int* __restrict__ off,
    const float* __restrict__ line_load,
    const float* __restrict__ bc_disp,
    const float* __restrict__ bc_rot,
    double* __restrict__ accum)
{
    __shared__ unsigned int acc3[NPBIN * 3];   // 12 KB, each word = 2 x bf16
    __shared__ float sm[16];
    int b = blockIdx.x;
    for (int i = threadIdx.x; i < NPBIN * 3; i += 1024) acc3[i] = 0u;
    __syncthreads();

    int s0 = off[b], s1 = off[b + 1];
    int nbase = b << CSH;
    unsigned int lds_base = (unsigned int)(unsigned long long)(&acc3[0]);

    int k = s0 + threadIdx.x;
    for (; k + 1024 < s1; k += 2048) {
        uint4 ea_ = ents[k];
        uint4 eb_ = ents[k + 1024];
        unsigned int aa = lds_base + ea_.w * 12u;
        unsigned int ab = lds_base + eb_.w * 12u;
        asm volatile(
            "ds_pk_add_bf16 %0, %2\n\t"
            "ds_pk_add_bf16 %0, %3 offset:4\n\t"
            "ds_pk_add_bf16 %0, %4 offset:8\n\t"
            "ds_pk_add_bf16 %1, %5\n\t"
            "ds_pk_add_bf16 %1, %6 offset:4\n\t"
            "ds_pk_add_bf16 %1, %7 offset:8"
            :: "v"(aa), "v"(ab),
               "v"(ea_.x), "v"(ea_.y), "v"(ea_.z),
               "v"(eb_.x), "v"(eb_.y), "v"(eb_.z)
            : "memory");
    }
    if (k < s1) {
        uint4 e = ents[k];
        unsigned int a = lds_base + e.w * 12u;
        asm volatile(
            "ds_pk_add_bf16 %0, %1\n\t"
            "ds_pk_add_bf16 %0, %2 offset:4\n\t"
            "ds_pk_add_bf16 %0, %3 offset:8"
            :: "v"(a), "v"(e.x), "v"(e.y), "v"(e.z)
            : "memory");
    }
    asm volatile("s_waitcnt lgkmcnt(0)" ::: "memory");
    __syncthreads();

    float sqF = 0.f, sqM = 0.f, fd = 0.f, fr = 0.f;
    for (int nl = threadIdx.x; nl < NPBIN; nl += 1024) {
        int n = nbase + nl;
        if (n < N_NODES) {
            float fdv = (bc_disp[n] < 0.5f) ? 1.f : 0.f;
            float frv = (bc_rot[n]  < 0.5f) ? 1.f : 0.f;
            unsigned int w0 = acc3[nl * 3 + 0];
            unsigned int w1 = acc3[nl * 3 + 1];
            unsigned int w2 = acc3[nl * 3 + 2];
            float Fr0 = unlo(w0) + line_load[3l * n + 0];
            float Fr1 = unhi(w0) + line_load[3l * n + 1];
            float Fr2 = unlo(w1) + line_load[3l * n + 2];
            float M0 = unhi(w1);
            float M1 = unlo(w2);
            float M2 = unhi(w2);
            sqF += fdv * (Fr0 * Fr0 + Fr1 * Fr1 + Fr2 * Fr2);
            sqM += frv * (M0 * M0 + M1 * M1 + M2 * M2);
            fd += fdv;
            fr += frv;
        }
    }
    block_reduce_add<16>(sqF, &accum[2], sm);
    block_reduce_add<16>(sqM, &accum[3], sm);
    block_reduce_add<16>(fd,  &accum[4], sm);
    block_reduce_add<16>(fr,  &accum[5], sm);
}

__global__ void final_kernel(const double* __restrict__ accum,
                             float* __restrict__ out)
{
    double F_char = fmax(accum[0] / (double)N_ELEM, 1.0);
    double M_char = fmax(accum[1] / (double)N_ELEM, 1.0);
    double lf = accum[2] / (F_char * F_char) / fmax(accum[4] * 3.0, 1.0);
    double lm = accum[3] / (M_char * M_char) / fmax(accum[5] * 3.0, 1.0);
    out[0] = (float)(lf + lm);
}

// ---------------- fallback: round-1 direct-atomic path ----------------

__global__ __launch_bounds__(256) void elem_kernel_fb(
    const float* __restrict__ pred,
    const int*   __restrict__ conn,
    const float* __restrict__ dirs,
    const float* __restrict__ L_, const float* __restrict__ E_,
    const float* __restrict__ A_, const float* __restrict__ I_,
    float* __restrict__ F_total, float* __restrict__ M_total,
    double* __restrict__ accum)
{
    __shared__ float sm[4];
    int e = blockIdx.x * blockDim.x + threadIdx.x;
    float ea = 0.f, eil = 0.f;
    if (e < N_ELEM) {
        int ni = conn[2 * e], nj = conn[2 * e + 1];
        float x0 = dirs[3 * e + 0], x1 = dirs[3 * e + 1], x2 = dirs[3 * e + 2];
        float L = L_[e], E = E_[e], A = A_[e], I = I_[e];
        float F0, F1, F2, Mi0, Mi1, Mi2, Mj0, Mj1, Mj2;
        beam_full(x0, x1, x2, pred + 6l * ni, pred + 6l * nj, L, E, A, I,
                  F0, F1, F2, Mi0, Mi1, Mi2, Mj0, Mj1, Mj2);
        atomicAdd(&F_total[3l * ni + 0],  F0);
        atomicAdd(&F_total[3l * ni + 1],  F1);
        atomicAdd(&F_total[3l * ni + 2],  F2);
        atomicAdd(&F_total[3l * nj + 0], -F0);
        atomicAdd(&F_total[3l * nj + 1], -F1);
        atomicAdd(&F_total[3l * nj + 2], -F2);
        atomicAdd(&M_total[3l * ni + 0], Mi0);
        atomicAdd(&M_total[3l * ni + 1], Mi1);
        atomicAdd(&M_total[3l * ni + 2], Mi2);
        atomicAdd(&M_total[3l * nj + 0], Mj0);
        atomicAdd(&M_total[3l * nj + 1], Mj1);
        atomicAdd(&M_total[3l * nj + 2], Mj2);
        ea  = E * A;
        eil = E * I / L;
    }
    block_reduce_add<4>(ea,  &accum[0], sm);
    block_reduce_add<4>(eil, &accum[1], sm);
}

__global__ __launch_bounds__(256) void node_kernel_fb(
    const float* __restrict__ F_total, const float* __restrict__ M_total,
    const float* __restrict__ line_load,
    const float* __restrict__ bc_disp, const float* __restrict__ bc_rot,
    double* __restrict__ accum)
{
    __shared__ float sm[4];
    int n = blockIdx.x * blockDim.x + threadIdx.x;
    float sqF = 0.f, sqM = 0.f, fd = 0.f, fr = 0.f;
    if (n < N_NODES) {
        fd = (bc_disp[n] < 0.5f) ? 1.f : 0.f;
        fr = (bc_rot[n]  < 0.5f) ? 1.f : 0.f;
        float Fr0 = F_total[3l * n + 0] + line_load[3l * n + 0];
        float Fr1 = F_total[3l * n + 1] + line_load[3l * n + 1];
        float Fr2 = F_total[3l * n + 2] + line_load[3l * n + 2];
        float M0 = M_total[3l * n + 0];
        float M1 = M_total[3l * n + 1];
        float M2 = M_total[3l * n + 2];
        sqF = fd * (Fr0 * Fr0 + Fr1 * Fr1 + Fr2 * Fr2);
        sqM = fr * (M0 * M0 + M1 * M1 + M2 * M2);
    }
    block_reduce_add<4>(sqF, &accum[2], sm);
    block_reduce_add<4>(sqM, &accum[3], sm);
    block_reduce_add<4>(fd,  &accum[4], sm);
    block_reduce_add<4>(fr,  &accum[5], sm);
}

extern "C" void kernel_launch(void* const* d_in, const int* in_sizes, int n_in,
                              void* d_out, int out_size, void* d_ws, size_t ws_size,
                              hipStream_t stream) {
    const float* pred      = (const float*)d_in[0];
    const int*   conn      = (const int*)  d_in[1];
    const float* dirs      = (const float*)d_in[2];
    const float* lens      = (const float*)d_in[3];
    const float* prop_E    = (const float*)d_in[4];
    const float* prop_A    = (const float*)d_in[5];
    const float* prop_I    = (const float*)d_in[6];
    const float* line_load = (const float*)d_in[7];
    const float* bc_disp   = (const float*)d_in[8];
    const float* bc_rot    = (const float*)d_in[9];

    double* accum = (double*)d_ws;

    if (ws_size >= WS_NEED) {
        int* off = (int*)((char*)d_ws + 1024);
        int* cnt = (int*)((char*)d_ws + 8192);
        unsigned short* hist = (unsigned short*)((char*)d_ws + HIST_OFF);
        unsigned short* offs = (unsigned short*)((char*)d_ws + OFFS_OFF);
        uint4* pred16 = (uint4*)((char*)d_ws + P16_OFF);
        uint4* ents = (uint4*)((char*)d_ws + ENT_OFF);

        hipMemsetAsync(d_ws, 0, 16384, stream);  // accum + off + cnt

        prep_kernel<<<(N_NODES + 255) / 256, 256, 0, stream>>>(pred, pred16);
        count_kernel<<<SBLK, 256, 0, stream>>>(conn, hist);
        scan2_kernel<<<NBIN, 256, 0, stream>>>(hist, offs, cnt);
        scan_kernel<<<1, 512, 0, stream>>>(cnt, off);
        emit_kernel<<<SBLK, 1024, 0, stream>>>(pred16, conn, dirs, lens,
                                               prop_E, prop_A, prop_I,
                                               off, offs, ents, accum);
        binacc_kernel<<<NBIN, 1024, 0, stream>>>(ents, off, line_load, bc_disp,
                                                 bc_rot, accum);
    } else {
        float* F_total = (float*)((char*)d_ws + 64);
        float* M_total = F_total + (size_t)N_NODES * 3;
        hipMemsetAsync(d_ws, 0, 64 + 2ull * N_NODES * 3 * sizeof(float), stream);
        int be = (N_ELEM + 255) / 256;
        elem_kernel_fb<<<be, 256, 0, stream>>>(pred, conn, dirs, lens, prop_E,
                                               prop_A, prop_I, F_total, M_total, accum);
        int bn = (N_NODES + 255) / 256;
        node_kernel_fb<<<bn, 256, 0, stream>>>(F_total, M_total, line_load,
                                               bc_disp, bc_rot, accum);
    }
    final_kernel<<<1, 1, 0, stream>>>(accum, (float*)d_out);
}

// Round 14
// 187.901 us; speedup vs baseline: 1.6507x; 1.4070x over previous
//
#include <hip/hip_runtime.h>
#include <hip/hip_bf16.h>

#define N_NODES 500000
#define N_ELEM  2000000

#define CSH   10                        // 1024 nodes per bin
#define NPBIN (1 << CSH)                // 1024
#define NBIN  ((N_NODES + NPBIN - 1) >> CSH)   // 489
#define SBLK  256                       // emit blocks (and count partition)

#define SC8  16.0f                      // fp8 encode scale (into e4m3 normal range)
#define IS8  (1.0f / 16.0f)

typedef float floatx2 __attribute__((ext_vector_type(2)));

// ws layout:
//   [0,64)              double accum[8]
//   [1024, +4*(NBIN+1)) int off[NBIN+1]
//   [8192, +4*NBIN)     int cnt[NBIN]
//   [16384, +250368)    u16 hist[NBIN][SBLK]
//   [266752, +250368)   u16 offs[SBLK][NBIN]
//   [524288, +4MB)      uint2 pred8[N_NODES]   (8B per node, 6xfp8)
//   [.., +64MB)         uint4 entries[2*N_ELEM]
#define HIST_OFF 16384ull
#define OFFS_OFF 266752ull
#define P8_OFF   524288ull
#define ENT_OFF  (P8_OFF + 8ull * N_NODES)
#define WS_NEED  (ENT_OFF + 16ull * 2 * N_ELEM)

__device__ __forceinline__ float wave_reduce(float v) {
    #pragma unroll
    for (int o = 32; o > 0; o >>= 1) v += __shfl_down(v, o, 64);
    return v;
}

template<int NW>
__device__ __forceinline__ void block_reduce_add(float v, double* dst, float* sm) {
    int lane = threadIdx.x & 63;
    int wave = threadIdx.x >> 6;
    v = wave_reduce(v);
    if (lane == 0) sm[wave] = v;
    __syncthreads();
    if (threadIdx.x == 0) {
        float s = 0.f;
        #pragma unroll
        for (int w = 0; w < NW; ++w) s += sm[w];
        atomicAdd(dst, (double)s);
    }
    __syncthreads();
}

__device__ __forceinline__ unsigned int pack2(float a, float b) {
    unsigned int ua = (__float_as_uint(a) + 0x8000u) >> 16;
    unsigned int ub = (__float_as_uint(b) + 0x8000u) & 0xFFFF0000u;
    return ua | ub;
}
__device__ __forceinline__ float unlo(unsigned int u) {
    return __uint_as_float(u << 16);
}
__device__ __forceinline__ float unhi(unsigned int u) {
    return __uint_as_float(u & 0xFFFF0000u);
}

// ---------------- beam math ----------------
__device__ __forceinline__ void beam_core(
    float x0, float x1, float x2,
    float u0i, float u1i, float u2i, float t0i, float t1i, float t2i,
    float u0j, float u1j, float u2j, float t0j, float t1j, float t2j,
    float L, float E, float A, float I,
    float& F0, float& F1, float& F2,
    float& Mi0, float& Mi1, float& Mi2,
    float& Mj0, float& Mj1, float& Mj2)
{
    bool par = fabsf(x1) > 0.99f;
    float r1 = par ? 0.f : 1.f;
    float r2 = par ? 1.f : 0.f;
    float z0 = x1 * r2 - x2 * r1;
    float z1 = -x0 * r2;
    float z2 = x0 * r1;
    float zn = fmaxf(sqrtf(z0 * z0 + z1 * z1 + z2 * z2), 1e-8f);
    float izn = 1.f / zn;
    z0 *= izn; z1 *= izn; z2 *= izn;
    float y0 = z1 * x2 - z2 * x1;
    float y1 = z2 * x0 - z0 * x2;
    float y2 = z0 * x1 - z1 * x0;
    float yn = fmaxf(sqrtf(y0 * y0 + y1 * y1 + y2 * y2), 1e-8f);
    float iyn = 1.f / yn;
    y0 *= iyn; y1 *= iyn; y2 *= iyn;

    float du0 = u0j - u0i;
    float du1 = u1j - u1i;
    float du2 = u2j - u2i;

    float EA = E * A;
    float EI = E * I;
    float invL = 1.f / L;
    float invL2 = invL * invL;
    float invL3 = invL2 * invL;

    float axial = du0 * x0 + du1 * x1 + du2 * x2;
    float Naxial = EA * invL * axial;

    float k12 = 12.f * EI * invL3;
    float k6  = 6.f * EI * invL2;
    float kL  = EI * invL;

    float dwz = du0 * z0 + du1 * z1 + du2 * z2;
    float tyi = t0i * y0 + t1i * y1 + t2i * y2;
    float tyj = t0j * y0 + t1j * y1 + t2j * y2;
    float Vz  = k12 * dwz + k6 * (tyi + tyj);
    float Myi = k6 * dwz + kL * (2.f * tyi + tyj);
    float Myj = k6 * dwz + kL * (tyi + 2.f * tyj);

    float dwy = du0 * y0 + du1 * y1 + du2 * y2;
    float tzi = t0i * z0 + t1i * z1 + t2i * z2;
    float tzj = t0j * z0 + t1j * z1 + t2j * z2;
    float Vy  = k12 * dwy + k6 * (tzi + tzj);
    float Mzi = k6 * dwy + kL * (2.f * tzi + tzj);
    float Mzj = k6 * dwy + kL * (tzi + 2.f * tzj);

    F0 = Naxial * x0 + Vz * z0 + Vy * y0;
    F1 = Naxial * x1 + Vz * z1 + Vy * y1;
    F2 = Naxial * x2 + Vz * z2 + Vy * y2;

    Mi0 = Myi * y0 + Mzi * z0;
    Mi1 = Myi * y1 + Mzi * z1;
    Mi2 = Myi * y2 + Mzi * z2;
    Mj0 = Myj * y0 + Mzj * z0;
    Mj1 = Myj * y1 + Mzj * z1;
    Mj2 = Myj * y2 + Mzj * z2;
}

__device__ __forceinline__ void beam_full(
    float x0, float x1, float x2,
    const float* __restrict__ pi, const float* __restrict__ pj,
    float L, float E, float A, float I,
    float& F0, float& F1, float& F2,
    float& Mi0, float& Mi1, float& Mi2,
    float& Mj0, float& Mj1, float& Mj2)
{
    float2 a0 = *(const float2*)(pi + 0);
    float2 a1 = *(const float2*)(pi + 2);
    float2 a2 = *(const float2*)(pi + 4);
    float2 b0 = *(const float2*)(pj + 0);
    float2 b1 = *(const float2*)(pj + 2);
    float2 b2 = *(const float2*)(pj + 4);
    beam_core(x0, x1, x2,
              a0.x, a0.y, a1.x, a1.y, a2.x, a2.y,
              b0.x, b0.y, b1.x, b1.y, b2.x, b2.y,
              L, E, A, I,
              F0, F1, F2, Mi0, Mi1, Mi2, Mj0, Mj1, Mj2);
}

// ---------------- prep: pack pred into 8B fp8 rows (x16 scale) ----------------

__global__ __launch_bounds__(256) void prep_kernel(
    const float* __restrict__ pred, uint2* __restrict__ pred8)
{
    int n = blockIdx.x * 256 + threadIdx.x;
    if (n >= N_NODES) return;
    const float2* p2 = (const float2*)(pred + 6l * n);
    float2 a0 = p2[0], a1 = p2[1], a2 = p2[2];
    unsigned int lo = (unsigned int)__builtin_amdgcn_cvt_pk_fp8_f32(
                          a0.x * SC8, a0.y * SC8, 0, false);        // bytes0-1: u0,u1
    lo = (unsigned int)__builtin_amdgcn_cvt_pk_fp8_f32(
                          a1.x * SC8, a1.y * SC8, (int)lo, true);   // bytes2-3: u2,t0
    unsigned int hi = (unsigned int)__builtin_amdgcn_cvt_pk_fp8_f32(
                          a2.x * SC8, a2.y * SC8, 0, false);        // bytes0-1: t1,t2
    pred8[n] = make_uint2(lo, hi);
}

// ---------------- count: per-emit-block histogram ----------------

__global__ __launch_bounds__(256) void count_kernel(
    const int* __restrict__ conn, unsigned short* __restrict__ hist)
{
    __shared__ int bins[NBIN];
    for (int i = threadIdx.x; i < NBIN; i += 256) bins[i] = 0;
    __syncthreads();

    int b = blockIdx.x;
    int per = (N_ELEM + SBLK - 1) / SBLK;
    int e0 = b * per;
    int e1 = min(e0 + per, N_ELEM);
    const int2* c2 = (const int2*)conn;

    for (int e = e0 + threadIdx.x; e < e1; e += 256) {
        int2 c = c2[e];
        atomicAdd(&bins[c.x >> CSH], 1);
        atomicAdd(&bins[c.y >> CSH], 1);
    }
    __syncthreads();
    for (int k = threadIdx.x; k < NBIN; k += 256)
        hist[(size_t)k * SBLK + b] = (unsigned short)bins[k];
}

// per-bin scan across the 256 emit blocks
__global__ __launch_bounds__(256) void scan2_kernel(
    const unsigned short* __restrict__ hist,
    unsigned short* __restrict__ offs, int* __restrict__ cnt)
{
    __shared__ int s[256];
    int k = blockIdx.x, t = threadIdx.x;
    int v = hist[(size_t)k * SBLK + t];
    s[t] = v;
    __syncthreads();
    for (int o = 1; o < 256; o <<= 1) {
        int tv = (t >= o) ? s[t - o] : 0;
        __syncthreads();
        s[t] += tv;
        __syncthreads();
    }
    offs[(size_t)t * NBIN + k] = (unsigned short)(s[t] - v);
    if (t == 255) cnt[k] = s[t];
}

__global__ __launch_bounds__(512) void scan_kernel(
    const int* __restrict__ cnt, int* __restrict__ off)
{
    __shared__ int s[512];
    int tid = threadIdx.x;
    int v = (tid < NBIN) ? cnt[tid] : 0;
    s[tid] = v;
    __syncthreads();
    for (int o = 1; o < 512; o <<= 1) {
        int t = (tid >= o) ? s[tid - o] : 0;
        __syncthreads();
        s[tid] += t;
        __syncthreads();
    }
    if (tid < NBIN) off[tid] = s[tid] - v;
    if (tid == 511) off[NBIN] = s[511];
}

// ---------------- emit: fp8 pred gather + bf16 payload scatter ----------------

__global__ __launch_bounds__(1024) void emit_kernel(
    const uint2* __restrict__ pred8,
    const int* __restrict__ conn,
    const float* __restrict__ dirs,
    const float* __restrict__ L_, const float* __restrict__ E_,
    const float* __restrict__ A_, const float* __restrict__ I_,
    const int* __restrict__ off, const unsigned short* __restrict__ offs,
    uint4* __restrict__ ents, double* __restrict__ accum)
{
    __shared__ int bins[NBIN];
    __shared__ float sm[16];
    int b = blockIdx.x;
    for (int i = threadIdx.x; i < NBIN; i += 1024)
        bins[i] = off[i] + (int)offs[(size_t)b * NBIN + i];
    __syncthreads();

    int per = (N_ELEM + SBLK - 1) / SBLK;
    int e0 = b * per;
    int e1 = min(e0 + per, N_ELEM);
    const int2* c2 = (const int2*)conn;

    float ea = 0.f, eil = 0.f;
    for (int e = e0 + threadIdx.x; e < e1; e += 1024) {
        int2 c = c2[e];
        uint2 pi8 = pred8[c.x];           // single 8B gather per end
        uint2 pj8 = pred8[c.y];
        float x0 = dirs[3 * e + 0], x1 = dirs[3 * e + 1], x2 = dirs[3 * e + 2];
        float L = L_[e], E = E_[e], A = A_[e], I = I_[e];
        ea  += E * A;
        eil += E * I / L;

        floatx2 iuv = __builtin_amdgcn_cvt_pk_f32_fp8((int)pi8.x, false); // u0,u1
        floatx2 iut = __builtin_amdgcn_cvt_pk_f32_fp8((int)pi8.x, true);  // u2,t0
        floatx2 itt = __builtin_amdgcn_cvt_pk_f32_fp8((int)pi8.y, false); // t1,t2
        floatx2 juv = __builtin_amdgcn_cvt_pk_f32_fp8((int)pj8.x, false);
        floatx2 jut = __builtin_amdgcn_cvt_pk_f32_fp8((int)pj8.x, true);
        floatx2 jtt = __builtin_amdgcn_cvt_pk_f32_fp8((int)pj8.y, false);

        float F0, F1, F2, Mi0, Mi1, Mi2, Mj0, Mj1, Mj2;
        beam_core(x0, x1, x2,
                  iuv.x * IS8, iuv.y * IS8, iut.x * IS8,
                  iut.y * IS8, itt.x * IS8, itt.y * IS8,
                  juv.x * IS8, juv.y * IS8, jut.x * IS8,
                  jut.y * IS8, jtt.x * IS8, jtt.y * IS8,
                  L, E, A, I,
                  F0, F1, F2, Mi0, Mi1, Mi2, Mj0, Mj1, Mj2);

        int pi_ = atomicAdd(&bins[c.x >> CSH], 1);
        uint4 ei;
        ei.x = pack2(F0, F1);
        ei.y = pack2(F2, Mi0);
        ei.z = pack2(Mi1, Mi2);
        ei.w = (unsigned int)(c.x & (NPBIN - 1));
        ents[pi_] = ei;

        int pj_ = atomicAdd(&bins[c.y >> CSH], 1);
        uint4 ej;
        ej.x = pack2(-F0, -F1);
        ej.y = pack2(-F2, Mj0);
        ej.z = pack2(Mj1, Mj2);
        ej.w = (unsigned int)(c.y & (NPBIN - 1));
        ents[pj_] = ej;
    }
    block_reduce_add<16>(ea,  &accum[0], sm);
    block_reduce_add<16>(eil, &accum[1], sm);
}

// ---------------- bin accumulate via ds_pk_add_bf16 + fused node loss ----------------

__global__ __launch_bounds__(1024) void binacc_kernel(
    const uint4* __restrict__ ents,
    const int* __restrict__ off,
    const float* __restrict__ line_load,
    const float* __restrict__ bc_disp,
    const float* __restrict__ bc_rot,
    double* __restrict__ accum)
{
    __shared__ unsigned int acc3[NPBIN * 3];   // 12 KB, each word = 2 x bf16
    __shared__ float sm[16];
    int b = blockIdx.x;
    for (int i = threadIdx.x; i < NPBIN * 3; i += 1024) acc3[i] = 0u;
    __syncthreads();

    int s0 = off[b], s1 = off[b + 1];
    int nbase = b << CSH;
    unsigned int lds_base = (unsigned int)(unsigned long long)(&acc3[0]);

    int k = s0 + threadIdx.x;
    for (; k + 1024 < s1; k += 2048) {
        uint4 ea_ = ents[k];
        uint4 eb_ = ents[k + 1024];
        unsigned int aa = lds_base + ea_.w * 12u;
        unsigned int ab = lds_base + eb_.w * 12u;
        asm volatile(
            "ds_pk_add_bf16 %0, %2\n\t"
            "ds_pk_add_bf16 %0, %3 offset:4\n\t"
            "ds_pk_add_bf16 %0, %4 offset:8\n\t"
            "ds_pk_add_bf16 %1, %5\n\t"
            "ds_pk_add_bf16 %1, %6 offset:4\n\t"
            "ds_pk_add_bf16 %1, %7 offset:8"
            :: "v"(aa), "v"(ab),
               "v"(ea_.x), "v"(ea_.y), "v"(ea_.z),
               "v"(eb_.x), "v"(eb_.y), "v"(eb_.z)
            : "memory");
    }
    if (k < s1) {
        uint4 e = ents[k];
        unsigned int a = lds_base + e.w * 12u;
        asm volatile(
            "ds_pk_add_bf16 %0, %1\n\t"
            "ds_pk_add_bf16 %0, %2 offset:4\n\t"
            "ds_pk_add_bf16 %0, %3 offset:8"
            :: "v"(a), "v"(e.x), "v"(e.y), "v"(e.z)
            : "memory");
    }
    asm volatile("s_waitcnt lgkmcnt(0)" ::: "memory");
    __syncthreads();

    float sqF = 0.f, sqM = 0.f, fd = 0.f, fr = 0.f;
    for (int nl = threadIdx.x; nl < NPBIN; nl += 1024) {
        int n = nbase + nl;
        if (n < N_NODES) {
            float fdv = (bc_disp[n] < 0.5f) ? 1.f : 0.f;
            float frv = (bc_rot[n]  < 0.5f) ? 1.f : 0.f;
            unsigned int w0 = acc3[nl * 3 + 0];
            unsigned int w1 = acc3[nl * 3 + 1];
            unsigned int w2 = acc3[nl * 3 + 2];
            float Fr0 = unlo(w0) + line_load[3l * n + 0];
            float Fr1 = unhi(w0) + line_load[3l * n + 1];
            float Fr2 = unlo(w1) + line_load[3l * n + 2];
            float M0 = unhi(w1);
            float M1 = unlo(w2);
            float M2 = unhi(w2);
            sqF += fdv * (Fr0 * Fr0 + Fr1 * Fr1 + Fr2 * Fr2);
            sqM += frv * (M0 * M0 + M1 * M1 + M2 * M2);
            fd += fdv;
            fr += frv;
        }
    }
    block_reduce_add<16>(sqF, &accum[2], sm);
    block_reduce_add<16>(sqM, &accum[3], sm);
    block_reduce_add<16>(fd,  &accum[4], sm);
    block_reduce_add<16>(fr,  &accum[5], sm);
}

__global__ void final_kernel(const double* __restrict__ accum,
                             float* __restrict__ out)
{
    double F_char = fmax(accum[0] / (double)N_ELEM, 1.0);
    double M_char = fmax(accum[1] / (double)N_ELEM, 1.0);
    double lf = accum[2] / (F_char * F_char) / fmax(accum[4] * 3.0, 1.0);
    double lm = accum[3] / (M_char * M_char) / fmax(accum[5] * 3.0, 1.0);
    out[0] = (float)(lf + lm);
}

// ---------------- fallback: round-1 direct-atomic path ----------------

__global__ __launch_bounds__(256) void elem_kernel_fb(
    const float* __restrict__ pred,
    const int*   __restrict__ conn,
    const float* __restrict__ dirs,
    const float* __restrict__ L_, const float* __restrict__ E_,
    const float* __restrict__ A_, const float* __restrict__ I_,
    float* __restrict__ F_total, float* __restrict__ M_total,
    double* __restrict__ accum)
{
    __shared__ float sm[4];
    int e = blockIdx.x * blockDim.x + threadIdx.x;
    float ea = 0.f, eil = 0.f;
    if (e < N_ELEM) {
        int ni = conn[2 * e], nj = conn[2 * e + 1];
        float x0 = dirs[3 * e + 0], x1 = dirs[3 * e + 1], x2 = dirs[3 * e + 2];
        float L = L_[e], E = E_[e], A = A_[e], I = I_[e];
        float F0, F1, F2, Mi0, Mi1, Mi2, Mj0, Mj1, Mj2;
        beam_full(x0, x1, x2, pred + 6l * ni, pred + 6l * nj, L, E, A, I,
                  F0, F1, F2, Mi0, Mi1, Mi2, Mj0, Mj1, Mj2);
        atomicAdd(&F_total[3l * ni + 0],  F0);
        atomicAdd(&F_total[3l * ni + 1],  F1);
        atomicAdd(&F_total[3l * ni + 2],  F2);
        atomicAdd(&F_total[3l * nj + 0], -F0);
        atomicAdd(&F_total[3l * nj + 1], -F1);
        atomicAdd(&F_total[3l * nj + 2], -F2);
        atomicAdd(&M_total[3l * ni + 0], Mi0);
        atomicAdd(&M_total[3l * ni + 1], Mi1);
        atomicAdd(&M_total[3l * ni + 2], Mi2);
        atomicAdd(&M_total[3l * nj + 0], Mj0);
        atomicAdd(&M_total[3l * nj + 1], Mj1);
        atomicAdd(&M_total[3l * nj + 2], Mj2);
        ea  = E * A;
        eil = E * I / L;
    }
    block_reduce_add<4>(ea,  &accum[0], sm);
    block_reduce_add<4>(eil, &accum[1], sm);
}

__global__ __launch_bounds__(256) void node_kernel_fb(
    const float* __restrict__ F_total, const float* __restrict__ M_total,
    const float* __restrict__ line_load,
    const float* __restrict__ bc_disp, const float* __restrict__ bc_rot,
    double* __restrict__ accum)
{
    __shared__ float sm[4];
    int n = blockIdx.x * blockDim.x + threadIdx.x;
    float sqF = 0.f, sqM = 0.f, fd = 0.f, fr = 0.f;
    if (n < N_NODES) {
        fd = (bc_disp[n] < 0.5f) ? 1.f : 0.f;
        fr = (bc_rot[n]  < 0.5f) ? 1.f : 0.f;
        float Fr0 = F_total[3l * n + 0] + line_load[3l * n + 0];
        float Fr1 = F_total[3l * n + 1] + line_load[3l * n + 1];
        float Fr2 = F_total[3l * n + 2] + line_load[3l * n + 2];
        float M0 = M_total[3l * n + 0];
        float M1 = M_total[3l * n + 1];
        float M2 = M_total[3l * n + 2];
        sqF = fd * (Fr0 * Fr0 + Fr1 * Fr1 + Fr2 * Fr2);
        sqM = fr * (M0 * M0 + M1 * M1 + M2 * M2);
    }
    block_reduce_add<4>(sqF, &accum[2], sm);
    block_reduce_add<4>(sqM, &accum[3], sm);
    block_reduce_add<4>(fd,  &accum[4], sm);
    block_reduce_add<4>(fr,  &accum[5], sm);
}

extern "C" void kernel_launch(void* const* d_in, const int* in_sizes, int n_in,
                              void* d_out, int out_size, void* d_ws, size_t ws_size,
                              hipStream_t stream) {
    const float* pred      = (const float*)d_in[0];
    const int*   conn      = (const int*)  d_in[1];
    const float* dirs      = (const float*)d_in[2];
    const float* lens      = (const float*)d_in[3];
    const float* prop_E    = (const float*)d_in[4];
    const float* prop_A    = (const float*)d_in[5];
    const float* prop_I    = (const float*)d_in[6];
    const float* line_load = (const float*)d_in[7];
    const float* bc_disp   = (const float*)d_in[8];
    const float* bc_rot    = (const float*)d_in[9];

    double* accum = (double*)d_ws;

    if (ws_size >= WS_NEED) {
        int* off = (int*)((char*)d_ws + 1024);
        int* cnt = (int*)((char*)d_ws + 8192);
        unsigned short* hist = (unsigned short*)((char*)d_ws + HIST_OFF);
        unsigned short* offs = (unsigned short*)((char*)d_ws + OFFS_OFF);
        uint2* pred8 = (uint2*)((char*)d_ws + P8_OFF);
        uint4* ents = (uint4*)((char*)d_ws + ENT_OFF);

        hipMemsetAsync(d_ws, 0, 16384, stream);  // accum + off + cnt

        prep_kernel<<<(N_NODES + 255) / 256, 256, 0, stream>>>(pred, pred8);
        count_kernel<<<SBLK, 256, 0, stream>>>(conn, hist);
        scan2_kernel<<<NBIN, 256, 0, stream>>>(hist, offs, cnt);
        scan_kernel<<<1, 512, 0, stream>>>(cnt, off);
        emit_kernel<<<SBLK, 1024, 0, stream>>>(pred8, conn, dirs, lens,
                                               prop_E, prop_A, prop_I,
                                               off, offs, ents, accum);
        binacc_kernel<<<NBIN, 1024, 0, stream>>>(ents, off, line_load, bc_disp,
                                                 bc_rot, accum);
    } else {
        float* F_total = (float*)((char*)d_ws + 64);
        float* M_total = F_total + (size_t)N_NODES * 3;
        hipMemsetAsync(d_ws, 0, 64 + 2ull * N_NODES * 3 * sizeof(float), stream);
        int be = (N_ELEM + 255) / 256;
        elem_kernel_fb<<<be, 256, 0, stream>>>(pred, conn, dirs, lens, prop_E,
                                               prop_A, prop_I, F_total, M_total, accum);
        int bn = (N_NODES + 255) / 256;
        node_kernel_fb<<<bn, 256, 0, stream>>>(F_total, M_total, line_load,
                                               bc_disp, bc_rot, accum);
    }
    final_kernel<<<1, 1, 0, stream>>>(accum, (float*)d_out);
}

// Round 15
// 187.681 us; speedup vs baseline: 1.6527x; 1.0012x over previous
//
#include <hip/hip_runtime.h>
#include <hip/hip_bf16.h>

#define N_NODES 500000
#define N_ELEM  2000000

#define CSH   10                        // 1024 nodes per bin
#define NPBIN (1 << CSH)                // 1024
#define NBIN  ((N_NODES + NPBIN - 1) >> CSH)   // 489
#define SBLK  512                       // emit blocks (and count partition)

#define SC8  16.0f                      // fp8 encode scale (into e4m3 normal range)
#define IS8  (1.0f / 16.0f)

typedef float floatx2 __attribute__((ext_vector_type(2)));

// ws layout:
//   [0,64)              double accum[8]
//   [1024, +4*(NBIN+1)) int off[NBIN+1]
//   [8192, +4*NBIN)     int cnt[NBIN]
//   [16384, +2*NBIN*SBLK)  u16 hist[NBIN][SBLK]
//   [OFFS_OFF, +2*NBIN*SBLK) u16 offs[SBLK][NBIN]
//   [P8_OFF, +4MB)      uint2 pred8[N_NODES]   (8B per node, 6xfp8)
//   [ENT_OFF, +64MB)    uint4 entries[2*N_ELEM]
#define HIST_OFF 16384ull
#define OFFS_OFF (HIST_OFF + 2ull * NBIN * SBLK)            // 517120
#define P8_OFF   (OFFS_OFF + 2ull * NBIN * SBLK)            // 1017856 (8B aligned)
#define ENT_OFF  (P8_OFF + 8ull * N_NODES)                  // 5017856 (16B aligned)
#define WS_NEED  (ENT_OFF + 16ull * 2 * N_ELEM)

__device__ __forceinline__ float wave_reduce(float v) {
    #pragma unroll
    for (int o = 32; o > 0; o >>= 1) v += __shfl_down(v, o, 64);
    return v;
}

template<int NW>
__device__ __forceinline__ void block_reduce_add(float v, double* dst, float* sm) {
    int lane = threadIdx.x & 63;
    int wave = threadIdx.x >> 6;
    v = wave_reduce(v);
    if (lane == 0) sm[wave] = v;
    __syncthreads();
    if (threadIdx.x == 0) {
        float s = 0.f;
        #pragma unroll
        for (int w = 0; w < NW; ++w) s += sm[w];
        atomicAdd(dst, (double)s);
    }
    __syncthreads();
}

__device__ __forceinline__ unsigned int pack2(float a, float b) {
    unsigned int ua = (__float_as_uint(a) + 0x8000u) >> 16;
    unsigned int ub = (__float_as_uint(b) + 0x8000u) & 0xFFFF0000u;
    return ua | ub;
}
__device__ __forceinline__ float unlo(unsigned int u) {
    return __uint_as_float(u << 16);
}
__device__ __forceinline__ float unhi(unsigned int u) {
    return __uint_as_float(u & 0xFFFF0000u);
}

// ---------------- beam math ----------------
__device__ __forceinline__ void beam_core(
    float x0, float x1, float x2,
    float u0i, float u1i, float u2i, float t0i, float t1i, float t2i,
    float u0j, float u1j, float u2j, float t0j, float t1j, float t2j,
    float L, float E, float A, float I,
    float& F0, float& F1, float& F2,
    float& Mi0, float& Mi1, float& Mi2,
    float& Mj0, float& Mj1, float& Mj2)
{
    bool par = fabsf(x1) > 0.99f;
    float r1 = par ? 0.f : 1.f;
    float r2 = par ? 1.f : 0.f;
    float z0 = x1 * r2 - x2 * r1;
    float z1 = -x0 * r2;
    float z2 = x0 * r1;
    float zn = fmaxf(sqrtf(z0 * z0 + z1 * z1 + z2 * z2), 1e-8f);
    float izn = 1.f / zn;
    z0 *= izn; z1 *= izn; z2 *= izn;
    float y0 = z1 * x2 - z2 * x1;
    float y1 = z2 * x0 - z0 * x2;
    float y2 = z0 * x1 - z1 * x0;
    float yn = fmaxf(sqrtf(y0 * y0 + y1 * y1 + y2 * y2), 1e-8f);
    float iyn = 1.f / yn;
    y0 *= iyn; y1 *= iyn; y2 *= iyn;

    float du0 = u0j - u0i;
    float du1 = u1j - u1i;
    float du2 = u2j - u2i;

    float EA = E * A;
    float EI = E * I;
    float invL = 1.f / L;
    float invL2 = invL * invL;
    float invL3 = invL2 * invL;

    float axial = du0 * x0 + du1 * x1 + du2 * x2;
    float Naxial = EA * invL * axial;

    float k12 = 12.f * EI * invL3;
    float k6  = 6.f * EI * invL2;
    float kL  = EI * invL;

    float dwz = du0 * z0 + du1 * z1 + du2 * z2;
    float tyi = t0i * y0 + t1i * y1 + t2i * y2;
    float tyj = t0j * y0 + t1j * y1 + t2j * y2;
    float Vz  = k12 * dwz + k6 * (tyi + tyj);
    float Myi = k6 * dwz + kL * (2.f * tyi + tyj);
    float Myj = k6 * dwz + kL * (tyi + 2.f * tyj);

    float dwy = du0 * y0 + du1 * y1 + du2 * y2;
    float tzi = t0i * z0 + t1i * z1 + t2i * z2;
    float tzj = t0j * z0 + t1j * z1 + t2j * z2;
    float Vy  = k12 * dwy + k6 * (tzi + tzj);
    float Mzi = k6 * dwy + kL * (2.f * tzi + tzj);
    float Mzj = k6 * dwy + kL * (tzi + 2.f * tzj);

    F0 = Naxial * x0 + Vz * z0 + Vy * y0;
    F1 = Naxial * x1 + Vz * z1 + Vy * y1;
    F2 = Naxial * x2 + Vz * z2 + Vy * y2;

    Mi0 = Myi * y0 + Mzi * z0;
    Mi1 = Myi * y1 + Mzi * z1;
    Mi2 = Myi * y2 + Mzi * z2;
    Mj0 = Myj * y0 + Mzj * z0;
    Mj1 = Myj * y1 + Mzj * z1;
    Mj2 = Myj * y2 + Mzj * z2;
}

__device__ __forceinline__ void beam_full(
    float x0, float x1, float x2,
    const float* __restrict__ pi, const float* __restrict__ pj,
    float L, float E, float A, float I,
    float& F0, float& F1, float& F2,
    float& Mi0, float& Mi1, float& Mi2,
    float& Mj0, float& Mj1, float& Mj2)
{
    float2 a0 = *(const float2*)(pi + 0);
    float2 a1 = *(const float2*)(pi + 2);
    float2 a2 = *(const float2*)(pi + 4);
    float2 b0 = *(const float2*)(pj + 0);
    float2 b1 = *(const float2*)(pj + 2);
    float2 b2 = *(const float2*)(pj + 4);
    beam_core(x0, x1, x2,
              a0.x, a0.y, a1.x, a1.y, a2.x, a2.y,
              b0.x, b0.y, b1.x, b1.y, b2.x, b2.y,
              L, E, A, I,
              F0, F1, F2, Mi0, Mi1, Mi2, Mj0, Mj1, Mj2);
}

// ---------------- prep: pack pred into 8B fp8 rows (x16 scale) ----------------

__global__ __launch_bounds__(256) void prep_kernel(
    const float* __restrict__ pred, uint2* __restrict__ pred8)
{
    int n = blockIdx.x * 256 + threadIdx.x;
    if (n >= N_NODES) return;
    const float2* p2 = (const float2*)(pred + 6l * n);
    float2 a0 = p2[0], a1 = p2[1], a2 = p2[2];
    unsigned int lo = (unsigned int)__builtin_amdgcn_cvt_pk_fp8_f32(
                          a0.x * SC8, a0.y * SC8, 0, false);        // bytes0-1: u0,u1
    lo = (unsigned int)__builtin_amdgcn_cvt_pk_fp8_f32(
                          a1.x * SC8, a1.y * SC8, (int)lo, true);   // bytes2-3: u2,t0
    unsigned int hi = (unsigned int)__builtin_amdgcn_cvt_pk_fp8_f32(
                          a2.x * SC8, a2.y * SC8, 0, false);        // bytes0-1: t1,t2
    pred8[n] = make_uint2(lo, hi);
}

// ---------------- count: per-emit-block histogram ----------------

__global__ __launch_bounds__(256) void count_kernel(
    const int* __restrict__ conn, unsigned short* __restrict__ hist)
{
    __shared__ int bins[NBIN];
    for (int i = threadIdx.x; i < NBIN; i += 256) bins[i] = 0;
    __syncthreads();

    int b = blockIdx.x;
    int per = (N_ELEM + SBLK - 1) / SBLK;
    int e0 = b * per;
    int e1 = min(e0 + per, N_ELEM);
    const int2* c2 = (const int2*)conn;

    for (int e = e0 + threadIdx.x; e < e1; e += 256) {
        int2 c = c2[e];
        atomicAdd(&bins[c.x >> CSH], 1);
        atomicAdd(&bins[c.y >> CSH], 1);
    }
    __syncthreads();
    for (int k = threadIdx.x; k < NBIN; k += 256)
        hist[(size_t)k * SBLK + b] = (unsigned short)bins[k];
}

// per-bin scan across the SBLK emit blocks
__global__ __launch_bounds__(SBLK) void scan2_kernel(
    const unsigned short* __restrict__ hist,
    unsigned short* __restrict__ offs, int* __restrict__ cnt)
{
    __shared__ int s[SBLK];
    int k = blockIdx.x, t = threadIdx.x;
    int v = hist[(size_t)k * SBLK + t];
    s[t] = v;
    __syncthreads();
    for (int o = 1; o < SBLK; o <<= 1) {
        int tv = (t >= o) ? s[t - o] : 0;
        __syncthreads();
        s[t] += tv;
        __syncthreads();
    }
    offs[(size_t)t * NBIN + k] = (unsigned short)(s[t] - v);
    if (t == SBLK - 1) cnt[k] = s[t];
}

__global__ __launch_bounds__(512) void scan_kernel(
    const int* __restrict__ cnt, int* __restrict__ off)
{
    __shared__ int s[512];
    int tid = threadIdx.x;
    int v = (tid < NBIN) ? cnt[tid] : 0;
    s[tid] = v;
    __syncthreads();
    for (int o = 1; o < 512; o <<= 1) {
        int t = (tid >= o) ? s[tid - o] : 0;
        __syncthreads();
        s[tid] += t;
        __syncthreads();
    }
    if (tid < NBIN) off[tid] = s[tid] - v;
    if (tid == 511) off[NBIN] = s[511];
}

// ---------------- emit: fp8 pred gather + bf16 payload scatter ----------------

__global__ __launch_bounds__(1024) void emit_kernel(
    const uint2* __restrict__ pred8,
    const int* __restrict__ conn,
    const float* __restrict__ dirs,
    const float* __restrict__ L_, const float* __restrict__ E_,
    const float* __restrict__ A_, const float* __restrict__ I_,
    const int* __restrict__ off, const unsigned short* __restrict__ offs,
    uint4* __restrict__ ents, double* __restrict__ accum)
{
    __shared__ int bins[NBIN];
    __shared__ float sm[16];
    int b = blockIdx.x;
    for (int i = threadIdx.x; i < NBIN; i += 1024)
        bins[i] = off[i] + (int)offs[(size_t)b * NBIN + i];
    __syncthreads();

    int per = (N_ELEM + SBLK - 1) / SBLK;
    int e0 = b * per;
    int e1 = min(e0 + per, N_ELEM);
    const int2* c2 = (const int2*)conn;

    float ea = 0.f, eil = 0.f;
    for (int e = e0 + threadIdx.x; e < e1; e += 1024) {
        int2 c = c2[e];
        uint2 pi8 = pred8[c.x];           // single 8B gather per end
        uint2 pj8 = pred8[c.y];
        float x0 = dirs[3 * e + 0], x1 = dirs[3 * e + 1], x2 = dirs[3 * e + 2];
        float L = L_[e], E = E_[e], A = A_[e], I = I_[e];
        ea  += E * A;
        eil += E * I / L;

        floatx2 iuv = __builtin_amdgcn_cvt_pk_f32_fp8((int)pi8.x, false); // u0,u1
        floatx2 iut = __builtin_amdgcn_cvt_pk_f32_fp8((int)pi8.x, true);  // u2,t0
        floatx2 itt = __builtin_amdgcn_cvt_pk_f32_fp8((int)pi8.y, false); // t1,t2
        floatx2 juv = __builtin_amdgcn_cvt_pk_f32_fp8((int)pj8.x, false);
        floatx2 jut = __builtin_amdgcn_cvt_pk_f32_fp8((int)pj8.x, true);
        floatx2 jtt = __builtin_amdgcn_cvt_pk_f32_fp8((int)pj8.y, false);

        float F0, F1, F2, Mi0, Mi1, Mi2, Mj0, Mj1, Mj2;
        beam_core(x0, x1, x2,
                  iuv.x * IS8, iuv.y * IS8, iut.x * IS8,
                  iut.y * IS8, itt.x * IS8, itt.y * IS8,
                  juv.x * IS8, juv.y * IS8, jut.x * IS8,
                  jut.y * IS8, jtt.x * IS8, jtt.y * IS8,
                  L, E, A, I,
                  F0, F1, F2, Mi0, Mi1, Mi2, Mj0, Mj1, Mj2);

        int pi_ = atomicAdd(&bins[c.x >> CSH], 1);
        uint4 ei;
        ei.x = pack2(F0, F1);
        ei.y = pack2(F2, Mi0);
        ei.z = pack2(Mi1, Mi2);
        ei.w = (unsigned int)(c.x & (NPBIN - 1));
        ents[pi_] = ei;

        int pj_ = atomicAdd(&bins[c.y >> CSH], 1);
        uint4 ej;
        ej.x = pack2(-F0, -F1);
        ej.y = pack2(-F2, Mj0);
        ej.z = pack2(Mj1, Mj2);
        ej.w = (unsigned int)(c.y & (NPBIN - 1));
        ents[pj_] = ej;
    }
    block_reduce_add<16>(ea,  &accum[0], sm);
    block_reduce_add<16>(eil, &accum[1], sm);
}

// ---------------- bin accumulate via ds_pk_add_bf16 + fused node loss ----------------

__global__ __launch_bounds__(1024) void binacc_kernel(
    const uint4* __restrict__ ents,
    const int* __restrict__ off,
    const float* __restrict__ line_load,
    const float* __restrict__ bc_disp,
    const float* __restrict__ bc_rot,
    double* __restrict__ accum)
{
    __shared__ unsigned int acc3[NPBIN * 3];   // 12 KB, each word = 2 x bf16
    __shared__ float sm[16];
    int b = blockIdx.x;
    for (int i = threadIdx.x; i < NPBIN * 3; i += 1024) acc3[i] = 0u;
    __syncthreads();

    int s0 = off[b], s1 = off[b + 1];
    int nbase = b << CSH;
    unsigned int lds_base = (unsigned int)(unsigned long long)(&acc3[0]);

    int k = s0 + threadIdx.x;
    for (; k + 1024 < s1; k += 2048) {
        uint4 ea_ = ents[k];
        uint4 eb_ = ents[k + 1024];
        unsigned int aa = lds_base + ea_.w * 12u;
        unsigned int ab = lds_base + eb_.w * 12u;
        asm volatile(
            "ds_pk_add_bf16 %0, %2\n\t"
            "ds_pk_add_bf16 %0, %3 offset:4\n\t"
            "ds_pk_add_bf16 %0, %4 offset:8\n\t"
            "ds_pk_add_bf16 %1, %5\n\t"
            "ds_pk_add_bf16 %1, %6 offset:4\n\t"
            "ds_pk_add_bf16 %1, %7 offset:8"
            :: "v"(aa), "v"(ab),
               "v"(ea_.x), "v"(ea_.y), "v"(ea_.z),
               "v"(eb_.x), "v"(eb_.y), "v"(eb_.z)
            : "memory");
    }
    if (k < s1) {
        uint4 e = ents[k];
        unsigned int a = lds_base + e.w * 12u;
        asm volatile(
            "ds_pk_add_bf16 %0, %1\n\t"
            "ds_pk_add_bf16 %0, %2 offset:4\n\t"
            "ds_pk_add_bf16 %0, %3 offset:8"
            :: "v"(a), "v"(e.x), "v"(e.y), "v"(e.z)
            : "memory");
    }
    asm volatile("s_waitcnt lgkmcnt(0)" ::: "memory");
    __syncthreads();

    float sqF = 0.f, sqM = 0.f, fd = 0.f, fr = 0.f;
    for (int nl = threadIdx.x; nl < NPBIN; nl += 1024) {
        int n = nbase + nl;
        if (n < N_NODES) {
            float fdv = (bc_disp[n] < 0.5f) ? 1.f : 0.f;
            float frv = (bc_rot[n]  < 0.5f) ? 1.f : 0.f;
            unsigned int w0 = acc3[nl * 3 + 0];
            unsigned int w1 = acc3[nl * 3 + 1];
            unsigned int w2 = acc3[nl * 3 + 2];
            float Fr0 = unlo(w0) + line_load[3l * n + 0];
            float Fr1 = unhi(w0) + line_load[3l * n + 1];
            float Fr2 = unlo(w1) + line_load[3l * n + 2];
            float M0 = unhi(w1);
            float M1 = unlo(w2);
            float M2 = unhi(w2);
            sqF += fdv * (Fr0 * Fr0 + Fr1 * Fr1 + Fr2 * Fr2);
            sqM += frv * (M0 * M0 + M1 * M1 + M2 * M2);
            fd += fdv;
            fr += frv;
        }
    }
    block_reduce_add<16>(sqF, &accum[2], sm);
    block_reduce_add<16>(sqM, &accum[3], sm);
    block_reduce_add<16>(fd,  &accum[4], sm);
    block_reduce_add<16>(fr,  &accum[5], sm);
}

__global__ void final_kernel(const double* __restrict__ accum,
                             float* __restrict__ out)
{
    double F_char = fmax(accum[0] / (double)N_ELEM, 1.0);
    double M_char = fmax(accum[1] / (double)N_ELEM, 1.0);
    double lf = accum[2] / (F_char * F_char) / fmax(accum[4] * 3.0, 1.0);
    double lm = accum[3] / (M_char * M_char) / fmax(accum[5] * 3.0, 1.0);
    out[0] = (float)(lf + lm);
}

// ---------------- fallback: round-1 direct-atomic path ----------------

__global__ __launch_bounds__(256) void elem_kernel_fb(
    const float* __restrict__ pred,
    const int*   __restrict__ conn,
    const float* __restrict__ dirs,
    const float* __restrict__ L_, const float* __restrict__ E_,
    const float* __restrict__ A_, const float* __restrict__ I_,
    float* __restrict__ F_total, float* __restrict__ M_total,
    double* __restrict__ accum)
{
    __shared__ float sm[4];
    int e = blockIdx.x * blockDim.x + threadIdx.x;
    float ea = 0.f, eil = 0.f;
    if (e < N_ELEM) {
        int ni = conn[2 * e], nj = conn[2 * e + 1];
        float x0 = dirs[3 * e + 0], x1 = dirs[3 * e + 1], x2 = dirs[3 * e + 2];
        float L = L_[e], E = E_[e], A = A_[e], I = I_[e];
        float F0, F1, F2, Mi0, Mi1, Mi2, Mj0, Mj1, Mj2;
        beam_full(x0, x1, x2, pred + 6l * ni, pred + 6l * nj, L, E, A, I,
                  F0, F1, F2, Mi0, Mi1, Mi2, Mj0, Mj1, Mj2);
        atomicAdd(&F_total[3l * ni + 0],  F0);
        atomicAdd(&F_total[3l * ni + 1],  F1);
        atomicAdd(&F_total[3l * ni + 2],  F2);
        atomicAdd(&F_total[3l * nj + 0], -F0);
        atomicAdd(&F_total[3l * nj + 1], -F1);
        atomicAdd(&F_total[3l * nj + 2], -F2);
        atomicAdd(&M_total[3l * ni + 0], Mi0);
        atomicAdd(&M_total[3l * ni + 1], Mi1);
        atomicAdd(&M_total[3l * ni + 2], Mi2);
        atomicAdd(&M_total[3l * nj + 0], Mj0);
        atomicAdd(&M_total[3l * nj + 1], Mj1);
        atomicAdd(&M_total[3l * nj + 2], Mj2);
        ea  = E * A;
        eil = E * I / L;
    }
    block_reduce_add<4>(ea,  &accum[0], sm);
    block_reduce_add<4>(eil, &accum[1], sm);
}

__global__ __launch_bounds__(256) void node_kernel_fb(
    const float* __restrict__ F_total, const float* __restrict__ M_total,
    const float* __restrict__ line_load,
    const float* __restrict__ bc_disp, const float* __restrict__ bc_rot,
    double* __restrict__ accum)
{
    __shared__ float sm[4];
    int n = blockIdx.x * blockDim.x + threadIdx.x;
    float sqF = 0.f, sqM = 0.f, fd = 0.f, fr = 0.f;
    if (n < N_NODES) {
        fd = (bc_disp[n] < 0.5f) ? 1.f : 0.f;
        fr = (bc_rot[n]  < 0.5f) ? 1.f : 0.f;
        float Fr0 = F_total[3l * n + 0] + line_load[3l * n + 0];
        float Fr1 = F_total[3l * n + 1] + line_load[3l * n + 1];
        float Fr2 = F_total[3l * n + 2] + line_load[3l * n + 2];
        float M0 = M_total[3l * n + 0];
        float M1 = M_total[3l * n + 1];
        float M2 = M_total[3l * n + 2];
        sqF = fd * (Fr0 * Fr0 + Fr1 * Fr1 + Fr2 * Fr2);
        sqM = fr * (M0 * M0 + M1 * M1 + M2 * M2);
    }
    block_reduce_add<4>(sqF, &accum[2], sm);
    block_reduce_add<4>(sqM, &accum[3], sm);
    block_reduce_add<4>(fd,  &accum[4], sm);
    block_reduce_add<4>(fr,  &accum[5], sm);
}

extern "C" void kernel_launch(void* const* d_in, const int* in_sizes, int n_in,
                              void* d_out, int out_size, void* d_ws, size_t ws_size,
                              hipStream_t stream) {
    const float* pred      = (const float*)d_in[0];
    const int*   conn      = (const int*)  d_in[1];
    const float* dirs      = (const float*)d_in[2];
    const float* lens      = (const float*)d_in[3];
    const float* prop_E    = (const float*)d_in[4];
    const float* prop_A    = (const float*)d_in[5];
    const float* prop_I    = (const float*)d_in[6];
    const float* line_load = (const float*)d_in[7];
    const float* bc_disp   = (const float*)d_in[8];
    const float* bc_rot    = (const float*)d_in[9];

    double* accum = (double*)d_ws;

    if (ws_size >= WS_NEED) {
        int* off = (int*)((char*)d_ws + 1024);
        int* cnt = (int*)((char*)d_ws + 8192);
        unsigned short* hist = (unsigned short*)((char*)d_ws + HIST_OFF);
        unsigned short* offs = (unsigned short*)((char*)d_ws + OFFS_OFF);
        uint2* pred8 = (uint2*)((char*)d_ws + P8_OFF);
        uint4* ents = (uint4*)((char*)d_ws + ENT_OFF);

        hipMemsetAsync(d_ws, 0, 16384, stream);  // accum + off + cnt

        prep_kernel<<<(N_NODES + 255) / 256, 256, 0, stream>>>(pred, pred8);
        count_kernel<<<SBLK, 256, 0, stream>>>(conn, hist);
        scan2_kernel<<<NBIN, SBLK, 0, stream>>>(hist, offs, cnt);
        scan_kernel<<<1, 512, 0, stream>>>(cnt, off);
        emit_kernel<<<SBLK, 1024, 0, stream>>>(pred8, conn, dirs, lens,
                                               prop_E, prop_A, prop_I,
                                               off, offs, ents, accum);
        binacc_kernel<<<NBIN, 1024, 0, stream>>>(ents, off, line_load, bc_disp,
                                                 bc_rot, accum);
    } else {
        float* F_total = (float*)((char*)d_ws + 64);
        float* M_total = F_total + (size_t)N_NODES * 3;
        hipMemsetAsync(d_ws, 0, 64 + 2ull * N_NODES * 3 * sizeof(float), stream);
        int be = (N_ELEM + 255) / 256;
        elem_kernel_fb<<<be, 256, 0, stream>>>(pred, conn, dirs, lens, prop_E,
                                               prop_A, prop_I, F_total, M_total, accum);
        int bn = (N_NODES + 255) / 256;
        node_kernel_fb<<<bn, 256, 0, stream>>>(F_total, M_total, line_load,
                                               bc_disp, bc_rot, accum);
    }
    final_kernel<<<1, 1, 0, stream>>>(accum, (float*)d_out);
}